// Round 3
// baseline (1399.013 us; speedup 1.0000x reference)
//
#include <hip/hip_runtime.h>
#include <hip/hip_fp16.h>

typedef _Float16 h2 __attribute__((ext_vector_type(2)));
typedef unsigned int u32;

#define B_ 256
#define T_ 512
#define F_ 256
#define H_ 512

#define LDSQ 18   /* weight uint4-chunks (4 pairs each) in LDS  -> pairs 0..71   */
#define REGP 184  /* weight pairs resident in VGPRs             -> pairs 72..255 */

__device__ __forceinline__ float dot2f(u32 a, u32 b, float c) {
#if __has_builtin(__builtin_amdgcn_fdot2)
    return __builtin_amdgcn_fdot2(__builtin_bit_cast(h2, a), __builtin_bit_cast(h2, b), c, false);
#else
    h2 x = __builtin_bit_cast(h2, a), y = __builtin_bit_cast(h2, b);
    return c + (float)x[0] * (float)y[0] + (float)x[1] * (float)y[1];
#endif
}

__device__ __forceinline__ u32 packh2(float a, float b) {
    h2 v; v[0] = (_Float16)a; v[1] = (_Float16)b;
    return __builtin_bit_cast(u32, v);
}

// fast tanh: (e^{2x}-1)/(e^{2x}+1) with hw exp + rcp; clamp keeps exp in range.
__device__ __forceinline__ float fast_tanh(float x) {
    float t = fminf(fmaxf(x, -12.f), 12.f);
    float s = __expf(2.f * t);
    return 1.f - 2.f * __builtin_amdgcn_rcpf(s + 1.f);
}

// Pack Wx (128 pair-rows x 512) and Wh (256 pair-rows x 512) into f16x2.
__global__ void prepack_kernel(const float* __restrict__ Wx, const float* __restrict__ Wh,
                               u32* __restrict__ Wxpk, u32* __restrict__ Whpk) {
    int i = blockIdx.x * 256 + threadIdx.x;
    if (i < 128 * 512) {
        int p = i >> 9, j = i & 511;
        Wxpk[i] = packh2(Wx[(2 * p) * H_ + j], Wx[(2 * p + 1) * H_ + j]);
    }
    int k = i - 128 * 512;
    if (k >= 0 && k < 256 * 512) {
        int p = k >> 9, j = k & 511;
        Whpk[k] = packh2(Wh[(2 * p) * H_ + j], Wh[(2 * p + 1) * H_ + j]);
    }
}

// xp[row][j] = f16( sum_f x[row][f] * Wx[f][j] + b[j] ), 32 rows/block.
__global__ __launch_bounds__(512) void xp_gemm_kernel(const float* __restrict__ x,
                                                      const u32* __restrict__ Wxpk,
                                                      const float* __restrict__ b,
                                                      __half* __restrict__ xp) {
    __shared__ u32 ldsx[128 * 32];  // [p][r]: pair p (of 128) x row r (of 32)
    const int j = threadIdx.x;
    const long row0 = (long)blockIdx.x * 32;
    const float2* x2 = (const float2*)(x + row0 * F_);  // 32 rows * 128 float2
    for (int i = j; i < 128 * 32; i += 512) {
        int p = i >> 5, r = i & 31;
        float2 v = x2[r * 128 + p];
        ldsx[i] = packh2(v.x, v.y);
    }
    __syncthreads();
    const uint4* lx4 = (const uint4*)ldsx;
    float acc[32];
#pragma unroll
    for (int r = 0; r < 32; ++r) acc[r] = 0.f;
    u32 w = Wxpk[j];
    for (int p = 0; p < 128; ++p) {
        u32 wn = (p < 127) ? Wxpk[(p + 1) * 512 + j] : 0u;  // prefetch next
        uint4 a0 = lx4[p * 8 + 0], a1 = lx4[p * 8 + 1], a2 = lx4[p * 8 + 2], a3 = lx4[p * 8 + 3];
        uint4 a4 = lx4[p * 8 + 4], a5 = lx4[p * 8 + 5], a6 = lx4[p * 8 + 6], a7 = lx4[p * 8 + 7];
        u32 hv[32] = {a0.x, a0.y, a0.z, a0.w, a1.x, a1.y, a1.z, a1.w,
                      a2.x, a2.y, a2.z, a2.w, a3.x, a3.y, a3.z, a3.w,
                      a4.x, a4.y, a4.z, a4.w, a5.x, a5.y, a5.z, a5.w,
                      a6.x, a6.y, a6.z, a6.w, a7.x, a7.y, a7.z, a7.w};
#pragma unroll
        for (int r = 0; r < 32; ++r) acc[r] = dot2f(hv[r], w, acc[r]);
        w = wn;
    }
    float bj = b[j];
#pragma unroll
    for (int r = 0; r < 32; ++r)
        xp[(row0 + r) * H_ + j] = __float2half(acc[r] + bj);
}

// Persistent per-batch-row recurrence. 256 blocks x 512 threads (8 waves = 2/SIMD).
// amdgpu_waves_per_eu(2,2): register allocator budgets for exactly 2 waves/EU
// -> 256 VGPR/wave, so wreg[184] + ~40 working regs fit with NO spill.
__global__ __launch_bounds__(512)
__attribute__((amdgpu_waves_per_eu(2, 2)))
void rnn_kernel(const __half* __restrict__ xp,
                const u32* __restrict__ Whpk,
                const float* __restrict__ Wfc,
                const float* __restrict__ bfc,
                float* __restrict__ out) {
    extern __shared__ u32 lds[];
    // wq[c*512 + j] = uint4 of weight pairs {4c..4c+3} for column j, c in [0,18)
    uint4* wq = (uint4*)lds;                     // 18*512*16 = 147456 B
    __half* hb = (__half*)(lds + 18 * 512 * 4);  // 2 x 512 halfs (double buffer), 2048 B
    const int j = threadIdx.x;
    const int b = blockIdx.x;

    for (int c = 0; c < LDSQ; ++c) {
        uint4 v;
        v.x = Whpk[(4 * c + 0) * 512 + j];
        v.y = Whpk[(4 * c + 1) * 512 + j];
        v.z = Whpk[(4 * c + 2) * 512 + j];
        v.w = Whpk[(4 * c + 3) * 512 + j];
        wq[c * 512 + j] = v;
    }
    u32 wreg[REGP];
#pragma unroll
    for (int i = 0; i < REGP; ++i) wreg[i] = Whpk[(4 * LDSQ + i) * 512 + j];

    hb[j] = __float2half(0.f);
    hb[512 + j] = __float2half(0.f);
    const __half* xprow = xp + (size_t)b * T_ * H_ + j;
    float hn = 0.f;
    __syncthreads();
    float xpv = __half2float(xprow[0]);

    int cur = 0;
    for (int t = 0; t < T_; ++t) {
        float a0 = xpv, a1 = 0.f, a2 = 0.f, a3 = 0.f;
        int tn = (t + 1 < T_) ? (t + 1) : (T_ - 1);
        __half nxt = xprow[(size_t)tn * H_];  // prefetch next step's xp
        const uint4* h4 = (const uint4*)(hb + cur * 512);
        // LDS-resident weight pairs 0..71
#pragma unroll
        for (int c = 0; c < LDSQ; ++c) {
            uint4 hv = h4[c];
            uint4 wv = wq[c * 512 + j];
            a0 = dot2f(hv.x, wv.x, a0);
            a1 = dot2f(hv.y, wv.y, a1);
            a2 = dot2f(hv.z, wv.z, a2);
            a3 = dot2f(hv.w, wv.w, a3);
        }
        // register-resident weight pairs 72..255
#pragma unroll
        for (int c = 0; c < REGP / 4; ++c) {
            uint4 hv = h4[LDSQ + c];
            a0 = dot2f(hv.x, wreg[4 * c + 0], a0);
            a1 = dot2f(hv.y, wreg[4 * c + 1], a1);
            a2 = dot2f(hv.z, wreg[4 * c + 2], a2);
            a3 = dot2f(hv.w, wreg[4 * c + 3], a3);
        }
        hn = fast_tanh((a0 + a1) + (a2 + a3));
        hb[(cur ^ 1) * 512 + j] = __float2half(hn);
        xpv = __half2float(nxt);
        __syncthreads();
        cur ^= 1;
    }

    // epilogue: out[b] = h_last . Wfc + bfc - 0.05
    float v = hn * Wfc[j];
#pragma unroll
    for (int off = 32; off; off >>= 1) v += __shfl_down(v, off, 64);
    float* red = (float*)hb;  // reuse LDS (all reads of hb are done)
    int lane = j & 63, wid = j >> 6;
    if (lane == 0) red[wid] = v;
    __syncthreads();
    if (j == 0) {
        float s = 0.f;
        for (int w = 0; w < 8; ++w) s += red[w];
        out[b] = s + bfc[0] - 0.05f;
    }
}

extern "C" void kernel_launch(void* const* d_in, const int* in_sizes, int n_in,
                              void* d_out, int out_size, void* d_ws, size_t ws_size,
                              hipStream_t stream) {
    const float* x   = (const float*)d_in[0];
    const float* Wx  = (const float*)d_in[1];
    const float* Wh  = (const float*)d_in[2];
    const float* b   = (const float*)d_in[3];
    const float* Wfc = (const float*)d_in[4];
    const float* bfc = (const float*)d_in[5];
    float* out = (float*)d_out;

    char* ws = (char*)d_ws;
    __half* xp = (__half*)ws;                               // 134,217,728 B
    u32* Wxpk  = (u32*)(ws + 134217728);                    //     262,144 B
    u32* Whpk  = (u32*)(ws + 134217728 + 262144);           //     524,288 B

    prepack_kernel<<<768, 256, 0, stream>>>(Wx, Wh, Wxpk, Whpk);
    xp_gemm_kernel<<<(B_ * T_) / 32, 512, 0, stream>>>(x, Wxpk, b, xp);

    const int dyn = 18 * 512 * 16 + 2048;  // 149504 B
    (void)hipFuncSetAttribute((const void*)rnn_kernel,
                              hipFuncAttributeMaxDynamicSharedMemorySize, dyn);
    rnn_kernel<<<B_, 512, dyn, stream>>>(xp, Whpk, Wfc, bfc, out);
}

// Round 4
// 1229.786 us; speedup vs baseline: 1.1376x; 1.1376x over previous
//
#include <hip/hip_runtime.h>
#include <hip/hip_fp16.h>

typedef _Float16 h2 __attribute__((ext_vector_type(2)));
typedef unsigned int u32;

#define B_ 256
#define T_ 512
#define F_ 256
#define H_ 512

// rnn weight split: per thread 256 u32 total; 208 in regs/AGPR, 48 streamed from LDS
#define NREG 208  /* = 8 q * 26 pairs */
#define NLDS 48   /* = 8 q * 6 pairs  */

__device__ __forceinline__ float dot2f(u32 a, u32 b, float c) {
#if __has_builtin(__builtin_amdgcn_fdot2)
    return __builtin_amdgcn_fdot2(__builtin_bit_cast(h2, a), __builtin_bit_cast(h2, b), c, false);
#else
    h2 x = __builtin_bit_cast(h2, a), y = __builtin_bit_cast(h2, b);
    return c + (float)x[0] * (float)y[0] + (float)x[1] * (float)y[1];
#endif
}

__device__ __forceinline__ u32 packh2(float a, float b) {
    h2 v; v[0] = (_Float16)a; v[1] = (_Float16)b;
    return __builtin_bit_cast(u32, v);
}

__device__ __forceinline__ float fast_tanh(float x) {
    float t = fminf(fmaxf(x, -12.f), 12.f);
    float s = __expf(2.f * t);
    return 1.f - 2.f * __builtin_amdgcn_rcpf(s + 1.f);
}

// Prepack:
//   region 0: Wxpk[p*512+j], p in [0,128)           (for xp_gemm)      65536 u32
//   region 1: greg, flat[(i4*512+t)*4+s], i=4*i4+s in [0,208)         106496 u32
//   region 2: glds, flat[(ch*512+t)*4+s], m=4*ch+s in [0,48)           24576 u32
// rnn weight element for (i|m, t): q=i/26 p=i%26 (reg) or q=m/6 p=26+m%6 (lds);
//   w=t>>6, l=t&63, c=l+64q, k0=64w+2p -> pack(Wh[k0][c], Wh[k0+1][c])
__global__ __launch_bounds__(512) void prepack_kernel(const float* __restrict__ Wx,
                                                      const float* __restrict__ Wh,
                                                      u32* __restrict__ Wxpk,
                                                      u32* __restrict__ greg,
                                                      u32* __restrict__ glds) {
    int id = blockIdx.x * 512 + threadIdx.x;
    if (id < 65536) {
        int p = id >> 9, j = id & 511;
        Wxpk[id] = packh2(Wx[(2 * p) * H_ + j], Wx[(2 * p + 1) * H_ + j]);
    } else if (id < 65536 + 106496) {
        int k = id - 65536;
        int s = k & 3, i4 = k >> 11, t = (k >> 2) & 511;
        int i = 4 * i4 + s;
        int q = i / 26, p = i % 26;
        int w = t >> 6, l = t & 63;
        int c = l + 64 * q, k0 = 64 * w + 2 * p;
        greg[k] = packh2(Wh[k0 * H_ + c], Wh[(k0 + 1) * H_ + c]);
    } else {
        int k = id - 65536 - 106496;
        int s = k & 3, ch = k >> 11, t = (k >> 2) & 511;
        int m = 4 * ch + s;
        int q = m / 6, p = 26 + m % 6;
        int w = t >> 6, l = t & 63;
        int c = l + 64 * q, k0 = 64 * w + 2 * p;
        glds[k] = packh2(Wh[k0 * H_ + c], Wh[(k0 + 1) * H_ + c]);
    }
}

// xp[row][j] = f16( sum_f x[row][f] * Wx[f][j] + b[j] ), 16 rows/block (round-2 proven).
__global__ __launch_bounds__(512) void xp_gemm_kernel(const float* __restrict__ x,
                                                      const u32* __restrict__ Wxpk,
                                                      const float* __restrict__ b,
                                                      __half* __restrict__ xp) {
    __shared__ u32 ldsx[16 * 128];  // [p][r]
    const int j = threadIdx.x;
    const long row0 = (long)blockIdx.x * 16;
    const float2* x2 = (const float2*)(x + row0 * F_);
    for (int i = j; i < 16 * 128; i += 512) {
        int p = i >> 4, r = i & 15;
        float2 v = x2[r * 128 + p];
        ldsx[i] = packh2(v.x, v.y);
    }
    __syncthreads();
    const uint4* lx4 = (const uint4*)ldsx;
    float acc[16];
#pragma unroll
    for (int r = 0; r < 16; ++r) acc[r] = 0.f;
    for (int p = 0; p < 128; ++p) {
        u32 w = Wxpk[p * 512 + j];
        uint4 a0 = lx4[p * 4 + 0], a1 = lx4[p * 4 + 1], a2 = lx4[p * 4 + 2], a3 = lx4[p * 4 + 3];
        u32 hv[16] = {a0.x, a0.y, a0.z, a0.w, a1.x, a1.y, a1.z, a1.w,
                      a2.x, a2.y, a2.z, a2.w, a3.x, a3.y, a3.z, a3.w};
#pragma unroll
        for (int r = 0; r < 16; ++r) acc[r] = dot2f(hv[r], w, acc[r]);
    }
    float bj = b[j];
#pragma unroll
    for (int r = 0; r < 16; ++r)
        xp[(row0 + r) * H_ + j] = __float2half(acc[r] + bj);
}

// Wave-k-slice RNN: 256 blocks x 512 threads. Wave w owns k in [64w,64w+64)
// (h-slice = 128 B broadcast, 8 b128/thread instead of 64); lane l owns columns
// {l+64q}. Partials reduced across waves via 16 KB LDS, 2 barriers/step.
__global__ __launch_bounds__(512)
void rnn_kernel(const __half* __restrict__ xp,
                const u32* __restrict__ greg,
                const u32* __restrict__ glds,
                const float* __restrict__ Wfc,
                const float* __restrict__ bfc,
                float* __restrict__ out) {
    extern __shared__ u32 lds[];
    uint4* ldsw4 = (uint4*)lds;                      // 12*512 uint4 = 98304 B
    float* part  = (float*)(lds + 12 * 512 * 4);     // 8*512 f32   = 16384 B
    __half* hb   = (__half*)(lds + 12 * 512 * 4 + 4096);  // 2*512 f16 = 2048 B
    const int t = threadIdx.x;
    const int w = t >> 6;
    const int l = t & 63;
    const int b = blockIdx.x;

    u32 wregs[NREG];
    const uint4* greg4 = (const uint4*)greg;
#pragma unroll
    for (int i4 = 0; i4 < NREG / 4; ++i4) {
        uint4 v = greg4[i4 * 512 + t];
        wregs[4 * i4 + 0] = v.x; wregs[4 * i4 + 1] = v.y;
        wregs[4 * i4 + 2] = v.z; wregs[4 * i4 + 3] = v.w;
    }
    const uint4* glds4 = (const uint4*)glds;
    for (int c = 0; c < NLDS / 4; ++c) ldsw4[c * 512 + t] = glds4[c * 512 + t];

    hb[t] = __float2half(0.f);
    hb[512 + t] = __float2half(0.f);
    const __half* xprow = xp + (size_t)b * T_ * H_ + t;
    __syncthreads();
    float xpv = __half2float(xprow[0]);
    const uint4* hb4 = (const uint4*)hb;

    int cur = 0;
    float hn = 0.f;
    for (int ts = 0; ts < T_; ++ts) {
        // phase 1: wave's h k-slice (broadcast within wave): pairs 32w..32w+32
        u32 hsu[32];
        {
            const uint4* hsrc = hb4 + cur * 64 + w * 8;
#pragma unroll
            for (int i = 0; i < 8; ++i) {
                uint4 v = hsrc[i];
                hsu[4 * i + 0] = v.x; hsu[4 * i + 1] = v.y;
                hsu[4 * i + 2] = v.z; hsu[4 * i + 3] = v.w;
            }
        }
        // phase 2: streamed weights (full-BW b128, step-invariant data)
        u32 lwu[NLDS];
#pragma unroll
        for (int c = 0; c < NLDS / 4; ++c) {
            uint4 v = ldsw4[c * 512 + t];
            lwu[4 * c + 0] = v.x; lwu[4 * c + 1] = v.y;
            lwu[4 * c + 2] = v.z; lwu[4 * c + 3] = v.w;
        }
        // phase 3: dots — acc[q] = sum over 32 local k-pairs
        float acc[8];
#pragma unroll
        for (int q = 0; q < 8; ++q) acc[q] = 0.f;
#pragma unroll
        for (int q = 0; q < 8; ++q) {
#pragma unroll
            for (int p = 0; p < 26; ++p)
                acc[q] = dot2f(hsu[p], wregs[q * 26 + p], acc[q]);
#pragma unroll
            for (int pp = 0; pp < 6; ++pp)
                acc[q] = dot2f(hsu[26 + pp], lwu[q * 6 + pp], acc[q]);
        }
        // phase 4: partial writes (2-way bank aliasing = free)
#pragma unroll
        for (int q = 0; q < 8; ++q) part[w * 512 + l + 64 * q] = acc[q];
        int tn = (ts + 1 < T_) ? (ts + 1) : (T_ - 1);
        __half nxt = xprow[(size_t)tn * H_];  // global prefetch, no LDS dep
        __syncthreads();
        // phase 5: thread t gathers column t across 8 waves (coalesced reads)
        float s = xpv;
#pragma unroll
        for (int ww = 0; ww < 8; ++ww) s += part[ww * 512 + t];
        hn = fast_tanh(s);
        hb[(cur ^ 1) * 512 + t] = __float2half(hn);
        xpv = __half2float(nxt);
        __syncthreads();
        cur ^= 1;
    }

    // epilogue: out[b] = h_last . Wfc + bfc - 0.05  (thread t holds column t)
    float v = hn * Wfc[t];
#pragma unroll
    for (int off = 32; off; off >>= 1) v += __shfl_down(v, off, 64);
    float* red = part;  // reuse (all waves past final barrier)
    int lane = t & 63, wid = t >> 6;
    if (lane == 0) red[wid] = v;
    __syncthreads();
    if (t == 0) {
        float ssum = 0.f;
        for (int ww = 0; ww < 8; ++ww) ssum += red[ww];
        out[b] = ssum + bfc[0] - 0.05f;
    }
}

extern "C" void kernel_launch(void* const* d_in, const int* in_sizes, int n_in,
                              void* d_out, int out_size, void* d_ws, size_t ws_size,
                              hipStream_t stream) {
    const float* x   = (const float*)d_in[0];
    const float* Wx  = (const float*)d_in[1];
    const float* Wh  = (const float*)d_in[2];
    const float* b   = (const float*)d_in[3];
    const float* Wfc = (const float*)d_in[4];
    const float* bfc = (const float*)d_in[5];
    float* out = (float*)d_out;

    char* ws = (char*)d_ws;
    __half* xp = (__half*)ws;                         // 134,217,728 B
    u32* Wxpk  = (u32*)(ws + 134217728);              //     262,144 B
    u32* greg  = (u32*)(ws + 134217728 + 262144);     //     425,984 B
    u32* glds  = (u32*)(ws + 134217728 + 262144 + 425984);  // 98,304 B

    prepack_kernel<<<384, 512, 0, stream>>>(Wx, Wh, Wxpk, greg, glds);
    xp_gemm_kernel<<<(B_ * T_) / 16, 512, 0, stream>>>(x, Wxpk, b, xp);

    const int dyn = 12 * 512 * 16 + 16384 + 2048;  // 116736 B
    (void)hipFuncSetAttribute((const void*)rnn_kernel,
                              hipFuncAttributeMaxDynamicSharedMemorySize, dyn);
    rnn_kernel<<<B_, 512, dyn, stream>>>(xp, greg, glds, Wfc, bfc, out);
}

// Round 5
// 1139.772 us; speedup vs baseline: 1.2274x; 1.0790x over previous
//
#include <hip/hip_runtime.h>
#include <hip/hip_fp16.h>

typedef _Float16 h2 __attribute__((ext_vector_type(2)));
typedef unsigned int u32;

#define B_ 256
#define T_ 512
#define F_ 256
#define H_ 512

// Per thread: 256 weight pairs total. 216 resident (VGPR+AGPR), 40 streamed from LDS.
#define NREG 216
#define NCH  (NREG / 4)   /* 54 uint4 chunks */
#define NLDS 40
#define LCH  (NLDS / 4)   /* 10 uint4 chunks */

__device__ __forceinline__ float dot2f(u32 a, u32 b, float c) {
#if __has_builtin(__builtin_amdgcn_fdot2)
    return __builtin_amdgcn_fdot2(__builtin_bit_cast(h2, a), __builtin_bit_cast(h2, b), c, false);
#else
    h2 x = __builtin_bit_cast(h2, a), y = __builtin_bit_cast(h2, b);
    return c + (float)x[0] * (float)y[0] + (float)x[1] * (float)y[1];
#endif
}

__device__ __forceinline__ u32 packh2(float a, float b) {
    h2 v; v[0] = (_Float16)a; v[1] = (_Float16)b;
    return __builtin_bit_cast(u32, v);
}

__device__ __forceinline__ u32 pk2(float a, float b) {
#if __has_builtin(__builtin_amdgcn_cvt_pkrtz)
    return __builtin_bit_cast(u32, __builtin_amdgcn_cvt_pkrtz(a, b));
#else
    return packh2(a, b);
#endif
}

__device__ __forceinline__ float fast_tanh(float x) {
    float t = fminf(fmaxf(x, -12.f), 12.f);
    float s = __expf(2.f * t);
    return 1.f - 2.f * __builtin_amdgcn_rcpf(s + 1.f);
}

// Prepack regions (flat tid over 384*512 = 196608):
//   [0, 65536)          : Wxpk[p*512+j]                      (xp_gemm)
//   [65536, 176128)     : greg  — 54 uint4-chunks, i=4*i4+s in [0,216): q=i/27 p=i%27
//   [176128, 196608)    : glds  — 10 uint4-chunks, m=4*ch+s in [0,40):  q=m/5  p=27+m%5
// weight(i|m, t): w=t>>6 l=t&63 c=l+64q k0=64w+2p -> pack(Wh[k0][c], Wh[k0+1][c])
__global__ __launch_bounds__(512) void prepack_kernel(const float* __restrict__ Wx,
                                                      const float* __restrict__ Wh,
                                                      u32* __restrict__ Wxpk,
                                                      u32* __restrict__ greg,
                                                      u32* __restrict__ glds) {
    int id = blockIdx.x * 512 + threadIdx.x;
    if (id < 65536) {
        int p = id >> 9, j = id & 511;
        Wxpk[id] = packh2(Wx[(2 * p) * H_ + j], Wx[(2 * p + 1) * H_ + j]);
    } else if (id < 65536 + 110592) {
        int k = id - 65536;
        int s = k & 3, i4 = k >> 11, t = (k >> 2) & 511;
        int i = 4 * i4 + s;
        int q = i / 27, p = i % 27;
        int w = t >> 6, l = t & 63;
        int c = l + 64 * q, k0 = 64 * w + 2 * p;
        greg[k] = packh2(Wh[k0 * H_ + c], Wh[(k0 + 1) * H_ + c]);
    } else {
        int k = id - 65536 - 110592;
        int s = k & 3, ch = k >> 11, t = (k >> 2) & 511;
        int m = 4 * ch + s;
        int q = m / 5, p = 27 + m % 5;
        int w = t >> 6, l = t & 63;
        int c = l + 64 * q, k0 = 64 * w + 2 * p;
        glds[k] = packh2(Wh[k0 * H_ + c], Wh[(k0 + 1) * H_ + c]);
    }
}

// xp[row][j] = f16( sum_f x[row][f] * Wx[f][j] + b[j] ), 16 rows/block.
__global__ __launch_bounds__(512) void xp_gemm_kernel(const float* __restrict__ x,
                                                      const u32* __restrict__ Wxpk,
                                                      const float* __restrict__ b,
                                                      __half* __restrict__ xp) {
    __shared__ u32 ldsx[16 * 128];  // [p][r]
    const int j = threadIdx.x;
    const long row0 = (long)blockIdx.x * 16;
    const float2* x2 = (const float2*)(x + row0 * F_);
    for (int i = j; i < 16 * 128; i += 512) {
        int p = i >> 4, r = i & 15;
        float2 v = x2[r * 128 + p];
        ldsx[i] = packh2(v.x, v.y);
    }
    __syncthreads();
    const uint4* lx4 = (const uint4*)ldsx;
    float acc[16];
#pragma unroll
    for (int r = 0; r < 16; ++r) acc[r] = 0.f;
    for (int p = 0; p < 128; ++p) {
        u32 w = Wxpk[p * 512 + j];
        uint4 a0 = lx4[p * 4 + 0], a1 = lx4[p * 4 + 1], a2 = lx4[p * 4 + 2], a3 = lx4[p * 4 + 3];
        u32 hv[16] = {a0.x, a0.y, a0.z, a0.w, a1.x, a1.y, a1.z, a1.w,
                      a2.x, a2.y, a2.z, a2.w, a3.x, a3.y, a3.z, a3.w};
#pragma unroll
        for (int r = 0; r < 16; ++r) acc[r] = dot2f(hv[r], w, acc[r]);
    }
    float bj = b[j];
#pragma unroll
    for (int r = 0; r < 16; ++r)
        xp[(row0 + r) * H_ + j] = __float2half(acc[r] + bj);
}

// Wave-k-slice RNN, SGPR h-broadcast, single barrier per step.
// Wave w owns k in [64w,64w+64); lane l owns cols {l+64q}. After the gather,
// lane l of wave w holds h_new[64w+l] == exactly wave w's next k-slice, so h
// is redistributed in-wave via shfl_xor+cvt_pkrtz+readlane into 32 SGPRs —
// no LDS h buffer, no second barrier (partials double-buffered).
__global__ __launch_bounds__(512)
void rnn_kernel(const __half* __restrict__ xp,
                const u32* __restrict__ greg,
                const u32* __restrict__ glds,
                const float* __restrict__ Wfc,
                const float* __restrict__ bfc,
                float* __restrict__ out) {
    extern __shared__ u32 lds[];
    uint4* ldsw4 = (uint4*)lds;                   // 10*512 uint4 = 81920 B
    float* part  = (float*)(lds + LCH * 512 * 4); // 2 * 8*512 f32 = 32768 B
    const int t = threadIdx.x;
    const int w = t >> 6;
    const int l = t & 63;
    const int b = blockIdx.x;

    u32 wregs[NREG];
    const uint4* greg4 = (const uint4*)greg;
#pragma unroll
    for (int i4 = 0; i4 < NCH; ++i4) {
        uint4 v = greg4[i4 * 512 + t];
        wregs[4 * i4 + 0] = v.x; wregs[4 * i4 + 1] = v.y;
        wregs[4 * i4 + 2] = v.z; wregs[4 * i4 + 3] = v.w;
    }
    const uint4* glds4 = (const uint4*)glds;
    for (int c = 0; c < LCH; ++c) ldsw4[c * 512 + t] = glds4[c * 512 + t];

    const __half* xprow = xp + (size_t)b * T_ * H_ + t;
    float xpv = __half2float(xprow[0]);
    int hp[32];
#pragma unroll
    for (int p = 0; p < 32; ++p) hp[p] = 0;  // h0 = 0
    __syncthreads();

    float hn = 0.f;
    int buf = 0;
    for (int ts = 0; ts < T_; ++ts) {
        int tn = (ts + 1 < T_) ? (ts + 1) : ts;
        __half nxt = xprow[(size_t)tn * H_];  // global prefetch, independent
        float acc[8];
#pragma unroll
        for (int q = 0; q < 8; ++q) acc[q] = 0.f;
        // resident weight pairs p in [0,27)
#pragma unroll
        for (int p = 0; p < 27; ++p) {
#pragma unroll
            for (int q = 0; q < 8; ++q)
                acc[q] = dot2f((u32)hp[p], wregs[q * 27 + p], acc[q]);
        }
        // LDS-streamed weight pairs p in [27,32)
#pragma unroll
        for (int ch = 0; ch < LCH; ++ch) {
            uint4 v = ldsw4[ch * 512 + t];
            u32 vv[4] = {v.x, v.y, v.z, v.w};
#pragma unroll
            for (int s = 0; s < 4; ++s) {
                const int m = 4 * ch + s, q = m / 5, p = 27 + m % 5;
                acc[q] = dot2f((u32)hp[p], vv[s], acc[q]);
            }
        }
        float* pb = part + buf * 4096;
#pragma unroll
        for (int q = 0; q < 8; ++q) pb[w * 512 + l + 64 * q] = acc[q];  // 2-way alias = free
        __syncthreads();
        float s = xpv;
#pragma unroll
        for (int ww = 0; ww < 8; ++ww) s += pb[ww * 512 + t];  // coalesced
        hn = fast_tanh(s);
        xpv = __half2float(nxt);
        // redistribute h in-wave: even lane 2p ends up holding pack(h[64w+2p], h[64w+2p+1])
        float nb = __shfl_xor(hn, 1, 64);
        u32 pair = pk2(hn, nb);  // valid on even lanes (self, neighbor)
#pragma unroll
        for (int p = 0; p < 32; ++p)
            hp[p] = __builtin_amdgcn_readlane((int)pair, 2 * p);
        buf ^= 1;
    }

    // epilogue: out[b] = h_last . Wfc + bfc - 0.05  (thread t holds column t)
    __syncthreads();  // all gathers done before reusing part as scratch
    float v = hn * Wfc[t];
#pragma unroll
    for (int off = 32; off; off >>= 1) v += __shfl_down(v, off, 64);
    float* red = part;
    if (l == 0) red[w] = v;
    __syncthreads();
    if (t == 0) {
        float ssum = 0.f;
        for (int ww = 0; ww < 8; ++ww) ssum += red[ww];
        out[b] = ssum + bfc[0] - 0.05f;
    }
}

extern "C" void kernel_launch(void* const* d_in, const int* in_sizes, int n_in,
                              void* d_out, int out_size, void* d_ws, size_t ws_size,
                              hipStream_t stream) {
    const float* x   = (const float*)d_in[0];
    const float* Wx  = (const float*)d_in[1];
    const float* Wh  = (const float*)d_in[2];
    const float* b   = (const float*)d_in[3];
    const float* Wfc = (const float*)d_in[4];
    const float* bfc = (const float*)d_in[5];
    float* out = (float*)d_out;

    char* ws = (char*)d_ws;
    __half* xp = (__half*)ws;                                  // 134,217,728 B
    u32* Wxpk  = (u32*)(ws + 134217728);                       //     262,144 B
    u32* greg  = (u32*)(ws + 134217728 + 262144);              //     442,368 B
    u32* glds  = (u32*)(ws + 134217728 + 262144 + 442368);     //      81,920 B

    prepack_kernel<<<384, 512, 0, stream>>>(Wx, Wh, Wxpk, greg, glds);
    xp_gemm_kernel<<<(B_ * T_) / 16, 512, 0, stream>>>(x, Wxpk, b, xp);

    const int dyn = LCH * 512 * 16 + 2 * 8 * 512 * 4;  // 81920 + 32768 = 114688 B
    (void)hipFuncSetAttribute((const void*)rnn_kernel,
                              hipFuncAttributeMaxDynamicSharedMemorySize, dyn);
    rnn_kernel<<<B_, 512, dyn, stream>>>(xp, greg, glds, Wfc, bfc, out);
}

// Round 6
// 1105.766 us; speedup vs baseline: 1.2652x; 1.0308x over previous
//
#include <hip/hip_runtime.h>
#include <hip/hip_fp16.h>

typedef _Float16 h2 __attribute__((ext_vector_type(2)));
typedef unsigned int u32;

#define B_ 256
#define T_ 512
#define F_ 256
#define H_ 512

// Per thread: 256 weight pairs total. 224 resident (VGPR+AGPR), 32 streamed from LDS.
#define NREG 224
#define NCH  (NREG / 4)   /* 56 uint4 chunks */
#define NLDS 32
#define LCH  (NLDS / 4)   /* 8 uint4 chunks; chunk ch -> q=ch, pairs 28..31 */

__device__ __forceinline__ float dot2f(u32 a, u32 b, float c) {
#if __has_builtin(__builtin_amdgcn_fdot2)
    return __builtin_amdgcn_fdot2(__builtin_bit_cast(h2, a), __builtin_bit_cast(h2, b), c, false);
#else
    h2 x = __builtin_bit_cast(h2, a), y = __builtin_bit_cast(h2, b);
    return c + (float)x[0] * (float)y[0] + (float)x[1] * (float)y[1];
#endif
}

__device__ __forceinline__ u32 packh2(float a, float b) {
    h2 v; v[0] = (_Float16)a; v[1] = (_Float16)b;
    return __builtin_bit_cast(u32, v);
}

__device__ __forceinline__ u32 pk2(float a, float b) {
#if __has_builtin(__builtin_amdgcn_cvt_pkrtz)
    return __builtin_bit_cast(u32, __builtin_amdgcn_cvt_pkrtz(a, b));
#else
    return packh2(a, b);
#endif
}

__device__ __forceinline__ float fast_tanh(float x) {
    float t = fminf(fmaxf(x, -12.f), 12.f);
    float s = __expf(2.f * t);
    return 1.f - 2.f * __builtin_amdgcn_rcpf(s + 1.f);
}

// Prepack regions (flat tid over 384*512 = 196608):
//   [0, 65536)        : Wxpk4 — [(p4*512+j)*4+s], p=4*p4+s in [0,128)   (xp_gemm, dwordx4)
//   [65536, 180224)   : greg  — 56 uint4-chunks, i=4*i4+s in [0,224): q=i/28 p=i%28
//   [180224, 196608)  : glds  — 8 uint4-chunks,  m=4*ch+s in [0,32):  q=ch   p=28+s
// rnn weight(i|m, t): w=t>>6 l=t&63 c=l+64q k0=64w+2p -> pack(Wh[k0][c], Wh[k0+1][c])
__global__ __launch_bounds__(512) void prepack_kernel(const float* __restrict__ Wx,
                                                      const float* __restrict__ Wh,
                                                      u32* __restrict__ Wxpk4,
                                                      u32* __restrict__ greg,
                                                      u32* __restrict__ glds) {
    int id = blockIdx.x * 512 + threadIdx.x;
    if (id < 65536) {
        int s = id & 3, j = (id >> 2) & 511, p4 = id >> 11;
        int p = 4 * p4 + s;
        Wxpk4[id] = packh2(Wx[(2 * p) * H_ + j], Wx[(2 * p + 1) * H_ + j]);
    } else if (id < 65536 + 114688) {
        int k = id - 65536;
        int s = k & 3, i4 = k >> 11, t = (k >> 2) & 511;
        int i = 4 * i4 + s;
        int q = i / 28, p = i % 28;
        int w = t >> 6, l = t & 63;
        int c = l + 64 * q, k0 = 64 * w + 2 * p;
        greg[k] = packh2(Wh[k0 * H_ + c], Wh[(k0 + 1) * H_ + c]);
    } else {
        int k = id - 65536 - 114688;
        int s = k & 3, ch = k >> 11, t = (k >> 2) & 511;
        int q = ch, p = 28 + s;
        int w = t >> 6, l = t & 63;
        int c = l + 64 * q, k0 = 64 * w + 2 * p;
        glds[k] = packh2(Wh[k0 * H_ + c], Wh[(k0 + 1) * H_ + c]);
    }
}

// xp[row][j] = f16( sum_f x[row][f] * Wx[f][j] + b[j] ), 16 rows/block.
// Weights as dwordx4 (4 k-pairs per load) + depth-1 prefetch: one 16B global
// load per 64 dot2 instead of one 4B load per 16 — kills the latency serialization.
__global__ __launch_bounds__(512) void xp_gemm_kernel(const float* __restrict__ x,
                                                      const uint4* __restrict__ Wxpk4,
                                                      const float* __restrict__ b,
                                                      __half* __restrict__ xp) {
    __shared__ u32 ldsx[16 * 128];  // [p][r]
    const int j = threadIdx.x;
    const long row0 = (long)blockIdx.x * 16;
    const float2* x2 = (const float2*)(x + row0 * F_);
    for (int i = j; i < 16 * 128; i += 512) {
        int p = i >> 4, r = i & 15;
        float2 v = x2[r * 128 + p];
        ldsx[i] = packh2(v.x, v.y);
    }
    __syncthreads();
    const uint4* lx4 = (const uint4*)ldsx;
    float acc[16];
#pragma unroll
    for (int r = 0; r < 16; ++r) acc[r] = 0.f;
    uint4 w = Wxpk4[j];  // p4 = 0
    for (int p4 = 0; p4 < 32; ++p4) {
        uint4 wn;
        if (p4 < 31) wn = Wxpk4[(p4 + 1) * 512 + j];  // prefetch next 4 pairs
        u32 ws[4] = {w.x, w.y, w.z, w.w};
#pragma unroll
        for (int s = 0; s < 4; ++s) {
            const int p = 4 * p4 + s;
            uint4 a0 = lx4[p * 4 + 0], a1 = lx4[p * 4 + 1], a2 = lx4[p * 4 + 2], a3 = lx4[p * 4 + 3];
            u32 hv[16] = {a0.x, a0.y, a0.z, a0.w, a1.x, a1.y, a1.z, a1.w,
                          a2.x, a2.y, a2.z, a2.w, a3.x, a3.y, a3.z, a3.w};
#pragma unroll
            for (int r = 0; r < 16; ++r) acc[r] = dot2f(hv[r], ws[s], acc[r]);
        }
        w = wn;
    }
    float bj = b[j];
#pragma unroll
    for (int r = 0; r < 16; ++r)
        xp[(row0 + r) * H_ + j] = __float2half(acc[r] + bj);
}

// Wave-k-slice RNN, SGPR h-broadcast, single barrier per step (round-5 structure).
__global__ __launch_bounds__(512)
void rnn_kernel(const __half* __restrict__ xp,
                const u32* __restrict__ greg,
                const u32* __restrict__ glds,
                const float* __restrict__ Wfc,
                const float* __restrict__ bfc,
                float* __restrict__ out) {
    extern __shared__ u32 lds[];
    uint4* ldsw4 = (uint4*)lds;                   // 8*512 uint4 = 65536 B
    float* part  = (float*)(lds + LCH * 512 * 4); // 2 * 8*512 f32 = 32768 B
    const int t = threadIdx.x;
    const int w = t >> 6;
    const int l = t & 63;
    const int b = blockIdx.x;

    u32 wregs[NREG];
    const uint4* greg4 = (const uint4*)greg;
#pragma unroll
    for (int i4 = 0; i4 < NCH; ++i4) {
        uint4 v = greg4[i4 * 512 + t];
        wregs[4 * i4 + 0] = v.x; wregs[4 * i4 + 1] = v.y;
        wregs[4 * i4 + 2] = v.z; wregs[4 * i4 + 3] = v.w;
    }
    const uint4* glds4 = (const uint4*)glds;
    for (int c = 0; c < LCH; ++c) ldsw4[c * 512 + t] = glds4[c * 512 + t];

    const __half* xprow = xp + (size_t)b * T_ * H_ + t;
    float xpv = __half2float(xprow[0]);
    int hp[32];
#pragma unroll
    for (int p = 0; p < 32; ++p) hp[p] = 0;  // h0 = 0
    __syncthreads();

    float hn = 0.f;
    int buf = 0;
    for (int ts = 0; ts < T_; ++ts) {
        int tn = (ts + 1 < T_) ? (ts + 1) : ts;
        __half nxt = xprow[(size_t)tn * H_];  // global prefetch, independent
        float acc[8];
#pragma unroll
        for (int q = 0; q < 8; ++q) acc[q] = 0.f;
        // resident weight pairs p in [0,28)
#pragma unroll
        for (int p = 0; p < 28; ++p) {
#pragma unroll
            for (int q = 0; q < 8; ++q)
                acc[q] = dot2f((u32)hp[p], wregs[q * 28 + p], acc[q]);
        }
        // LDS-streamed weight pairs p in [28,32): chunk ch feeds exactly acc[ch]
#pragma unroll
        for (int ch = 0; ch < LCH; ++ch) {
            uint4 v = ldsw4[ch * 512 + t];
            acc[ch] = dot2f((u32)hp[28], v.x, acc[ch]);
            acc[ch] = dot2f((u32)hp[29], v.y, acc[ch]);
            acc[ch] = dot2f((u32)hp[30], v.z, acc[ch]);
            acc[ch] = dot2f((u32)hp[31], v.w, acc[ch]);
        }
        float* pb = part + buf * 4096;
#pragma unroll
        for (int q = 0; q < 8; ++q) pb[w * 512 + l + 64 * q] = acc[q];  // 2-way alias = free
        __syncthreads();
        float s = xpv;
#pragma unroll
        for (int ww = 0; ww < 8; ++ww) s += pb[ww * 512 + t];  // coalesced
        hn = fast_tanh(s);
        xpv = __half2float(nxt);
        // redistribute h in-wave: even lane 2p holds pack(h[64w+2p], h[64w+2p+1])
        float nb = __shfl_xor(hn, 1, 64);
        u32 pair = pk2(hn, nb);
#pragma unroll
        for (int p = 0; p < 32; ++p)
            hp[p] = __builtin_amdgcn_readlane((int)pair, 2 * p);
        buf ^= 1;
    }

    // epilogue: out[b] = h_last . Wfc + bfc - 0.05  (thread t holds column t)
    __syncthreads();
    float v = hn * Wfc[t];
#pragma unroll
    for (int off = 32; off; off >>= 1) v += __shfl_down(v, off, 64);
    float* red = part;
    if (l == 0) red[w] = v;
    __syncthreads();
    if (t == 0) {
        float ssum = 0.f;
        for (int ww = 0; ww < 8; ++ww) ssum += red[ww];
        out[b] = ssum + bfc[0] - 0.05f;
    }
}

extern "C" void kernel_launch(void* const* d_in, const int* in_sizes, int n_in,
                              void* d_out, int out_size, void* d_ws, size_t ws_size,
                              hipStream_t stream) {
    const float* x   = (const float*)d_in[0];
    const float* Wx  = (const float*)d_in[1];
    const float* Wh  = (const float*)d_in[2];
    const float* b   = (const float*)d_in[3];
    const float* Wfc = (const float*)d_in[4];
    const float* bfc = (const float*)d_in[5];
    float* out = (float*)d_out;

    char* ws = (char*)d_ws;
    __half* xp  = (__half*)ws;                          // 134,217,728 B
    u32* Wxpk4  = (u32*)(ws + 134217728);               //     262,144 B
    u32* greg   = (u32*)(ws + 134479872);               //     458,752 B
    u32* glds   = (u32*)(ws + 134938624);               //      65,536 B

    prepack_kernel<<<384, 512, 0, stream>>>(Wx, Wh, Wxpk4, greg, glds);
    xp_gemm_kernel<<<(B_ * T_) / 16, 512, 0, stream>>>(x, (const uint4*)Wxpk4, b, xp);

    const int dyn = LCH * 512 * 16 + 2 * 8 * 512 * 4;  // 65536 + 32768 = 98304 B
    (void)hipFuncSetAttribute((const void*)rnn_kernel,
                              hipFuncAttributeMaxDynamicSharedMemorySize, dyn);
    rnn_kernel<<<B_, 512, dyn, stream>>>(xp, greg, glds, Wfc, bfc, out);
}